// Round 6
// baseline (900.236 us; speedup 1.0000x reference)
//
#include <hip/hip_runtime.h>

// QANet attention layer on MI355X (gfx950).
// B=40,S=128,H=768, NP=100, PL=20, HID=100, N=4000 sequences.
// Round 6: gemm_pre K-loop made DMA-free (no global_load_lds -> no vmcnt(0)
// drain at barriers): A f32 reg-prefetch distance 2, B bf16 reg distance 1,
// cvt_pk staging, 32KB LDS. bertW3 multiply fused into bgemm<1,1> A-load.

typedef unsigned short ushort_t;
typedef unsigned int u32;
typedef __attribute__((ext_vector_type(8))) short short8;
typedef __attribute__((ext_vector_type(4))) float f32x4;
typedef __attribute__((address_space(1))) const u32 gu32;
typedef __attribute__((address_space(3))) u32 lu32;

__device__ __forceinline__ ushort_t f2bf(float f) {
  u32 x = __builtin_bit_cast(u32, f);
  u32 r = (x + 0x7fffu + ((x >> 16) & 1u)) >> 16;
  return (ushort_t)r;
}
__device__ __forceinline__ float bflo(u32 u) { return __builtin_bit_cast(float, u << 16); }
__device__ __forceinline__ float bfhi(u32 u) { return __builtin_bit_cast(float, u & 0xffff0000u); }
__device__ __forceinline__ u32 cvtpk(float lo, float hi) {
  u32 r;
  asm("v_cvt_pk_bf16_f32 %0, %1, %2" : "=v"(r) : "v"(lo), "v"(hi));
  return r;
}

__device__ __forceinline__ float sigm(float x) { return 1.f / (1.f + __expf(-x)); }
__device__ __forceinline__ float tanh_f(float x) { return 1.f - 2.f / (__expf(2.f * x) + 1.f); }

// ---------------- prep kernels ----------------

__global__ void prep_weights(const float* __restrict__ Wih_f, const float* __restrict__ Wih_b,
                             const float* __restrict__ Whh_f, const float* __restrict__ Whh_b,
                             const float* __restrict__ bih_f, const float* __restrict__ bhh_f,
                             const float* __restrict__ bih_b, const float* __restrict__ bhh_b,
                             const float* __restrict__ projW, const float* __restrict__ attpW,
                             ushort_t* __restrict__ wihcat, ushort_t* __restrict__ whhcat,
                             float* __restrict__ biascat, ushort_t* __restrict__ projw_bf,
                             ushort_t* __restrict__ attpw_bf) {
  const int TOT = 614400 + 102400 + 800 + 196608 + 2359296;
  for (int idx = blockIdx.x * 256 + threadIdx.x; idx < TOT; idx += gridDim.x * 256) {
    if (idx < 614400) {                       // Wih cat [800][768]
      int g = idx / 768, k = idx % 768;
      float v = g < 400 ? Wih_f[g * 768 + k] : Wih_b[(g - 400) * 768 + k];
      wihcat[idx] = f2bf(v);
    } else if (idx < 716800) {                // Whh cat padded [2][400][128]
      int e = idx - 614400; int g = e / 128, j = e % 128;
      float v = 0.f;
      if (j < 100) v = g < 400 ? Whh_f[g * 100 + j] : Whh_b[(g - 400) * 100 + j];
      whhcat[e] = f2bf(v);
    } else if (idx < 717600) {                // bias cat [800]
      int g = idx - 716800;
      biascat[g] = g < 400 ? bih_f[g] + bhh_f[g] : bih_b[g - 400] + bhh_b[g - 400];
    } else if (idx < 914208) {                // projW padded [768][256]
      int e = idx - 717600; int o = e / 256, j = e % 256;
      float v = 0.f;
      if (j < 100) v = projW[o * 200 + j];
      else if (j >= 128 && j < 228) v = projW[o * 200 + 100 + (j - 128)];
      projw_bf[e] = f2bf(v);
    } else {                                  // attpW [768][3072]
      int e = idx - 914208;
      attpw_bf[e] = f2bf(attpW[e]);
    }
  }
}

// ---------------- fused convert + pre GEMM (v3: DMA-free K-loop) ----------------
// P[t][seqchunk][nq][off] = (x @ Wih^T + bias) bf16, off = s*16+lk*4+r.
// All staging via registers (T14): A(kt) loads issued at iter kt-2 (dist 2,
// covers HBM ~900cy), B(kt) at iter kt-1 (L2-hit). No global_load_lds in the
// loop -> barriers are pure syncs, prefetches survive them.

__global__ __launch_bounds__(256) void gemm_pre(
    const float* __restrict__ X,        // [4000][20][768] f32
    const ushort_t* __restrict__ B,     // wihcat [800][768]
    const float* __restrict__ bias,     // [800]
    ushort_t* __restrict__ P)
{
  __shared__ __align__(16) ushort_t lsA[128 * 64];
  __shared__ __align__(16) ushort_t lsB[128 * 64];
  // bijective XCD chunking: nwg=4375, q=546, r=7; bn fastest within bm
  int bid = blockIdx.x;
  int xcd = bid & 7, slot = bid >> 3;
  int L = (xcd < 7) ? xcd * 547 + slot : 3829 + slot;
  int bm = L / 7, bn = L - bm * 7;
  int m0 = bm * 128, n0 = bn * 128;
  int tid = threadIdx.x, lane = tid & 63, w = tid >> 6;
  int wr = w >> 1, wc = w & 1;
  int l15 = lane & 15, lk = lane >> 4;
  f32x4 acc[4][4];
  #pragma unroll
  for (int i = 0; i < 4; ++i)
    #pragma unroll
    for (int j = 0; j < 4; ++j)
      #pragma unroll
      for (int r = 0; r < 4; ++r) acc[i][j][r] = 0.f;

  // staging coords: thread covers rows srow+32i, 16B slot ss
  int srow = tid >> 3, ss = tid & 7;
  size_t abase[4];
  const ushort_t* bbase[4];
  #pragma unroll
  for (int i = 0; i < 4; ++i) {
    int m = m0 + srow + 32 * i;
    int t = m / 4000, sq = m - t * 4000;
    abase[i] = ((size_t)sq * 20 + t) * 768 + ss * 8;
    int n = n0 + srow + 32 * i;
    bbase[i] = B + (size_t)(n < 800 ? n : 0) * 768 + ss * 8;   // clamped rows masked at store
  }

  float4 paA[4][2], paB[4][2];
  uint4 pb[4];
  auto load_A = [&](int kt, float4 (&pa)[4][2]) {
    #pragma unroll
    for (int i = 0; i < 4; ++i) {
      const float* ap = X + abase[i] + kt * 64;
      pa[i][0] = *reinterpret_cast<const float4*>(ap);
      pa[i][1] = *reinterpret_cast<const float4*>(ap + 4);
    }
  };
  auto load_B = [&](int kt) {
    #pragma unroll
    for (int i = 0; i < 4; ++i)
      pb[i] = *reinterpret_cast<const uint4*>(bbase[i] + kt * 64);
  };
  auto iter = [&](int kt, float4 (&cur)[4][2]) {
    __syncthreads();   // MFMA(kt-1) reads done (pure sync: no DMA in flight)
    #pragma unroll
    for (int i = 0; i < 4; ++i) {
      int row = srow + 32 * i;
      int ph = (ss ^ (row & 7)) << 3;
      uint4 pk;
      pk.x = cvtpk(cur[i][0].x, cur[i][0].y);
      pk.y = cvtpk(cur[i][0].z, cur[i][0].w);
      pk.z = cvtpk(cur[i][1].x, cur[i][1].y);
      pk.w = cvtpk(cur[i][1].z, cur[i][1].w);
      *reinterpret_cast<uint4*>(&lsA[row * 64 + ph]) = pk;
      *reinterpret_cast<uint4*>(&lsB[row * 64 + ph]) = pb[i];
    }
    __syncthreads();   // stage visible
    if (kt + 2 < 12) load_A(kt + 2, cur);   // dist-2: buffer just freed
    if (kt + 1 < 12) load_B(kt + 1);        // dist-1: L2-resident weights
    #pragma unroll
    for (int ks = 0; ks < 2; ++ks) {
      short8 af[4], bfv[4];
      #pragma unroll
      for (int f = 0; f < 4; ++f) {
        int row = wr * 64 + f * 16 + l15;
        af[f] = *reinterpret_cast<const short8*>(
            &lsA[row * 64 + (((ks * 4 + lk) ^ (row & 7)) << 3)]);
        int rowb = wc * 64 + f * 16 + l15;
        bfv[f] = *reinterpret_cast<const short8*>(
            &lsB[rowb * 64 + (((ks * 4 + lk) ^ (rowb & 7)) << 3)]);
      }
      #pragma unroll
      for (int fm = 0; fm < 4; ++fm)
        #pragma unroll
        for (int fn = 0; fn < 4; ++fn)
          acc[fm][fn] = __builtin_amdgcn_mfma_f32_16x16x32_bf16(af[fm], bfv[fn], acc[fm][fn], 0, 0, 0);
    }
  };

  load_A(0, paA);
  load_B(0);
  load_A(1, paB);

  #pragma unroll 1
  for (int ktp = 0; ktp < 6; ++ktp) {
    iter(2 * ktp, paA);
    iter(2 * ktp + 1, paB);
  }

  // store in recurrence lane-layout (16-row frags never straddle t: 4000%16==0)
  #pragma unroll
  for (int fm = 0; fm < 4; ++fm) {
    int mb = m0 + wr * 64 + fm * 16;
    int t = mb / 4000;
    int sq = mb - t * 4000;
    int cch = sq >> 4;
    #pragma unroll
    for (int fn = 0; fn < 4; ++fn) {
      int nb = n0 + wc * 64 + fn * 16;
      if (nb < 800) {
        int nl = nb < 400 ? nb : nb - 400;
        int nq = (nb < 400 ? 0 : 25) + (nl >> 4);
        float bsv = bias[nb + l15];
        uint2 pk;
        pk.x = cvtpk(acc[fm][fn][0] + bsv, acc[fm][fn][1] + bsv);
        pk.y = cvtpk(acc[fm][fn][2] + bsv, acc[fm][fn][3] + bsv);
        *reinterpret_cast<uint2*>(
            &P[((((size_t)t * 250 + cch) * 50 + nq) << 8) + l15 * 16 + lk * 4]) = pk;
      }
    }
  }
}

// ---------------- 128x128 MFMA GEMM (global_load_lds) ----------------
// EPI 1: relu(v+bias); EPI 2: relu(v+bias)+resid.
// nbn>0: linear grid + bijective XCD-chunk swizzle (bn fastest within bm).

template <int EPI>
__global__ __launch_bounds__(256) void gemm128(
    const ushort_t* __restrict__ A, int lda,
    const ushort_t* __restrict__ B, int ldb,
    int M, int N, int KT,
    const float* __restrict__ bias,
    const float* __restrict__ resid,
    float* __restrict__ C, int ldc,
    int nbn, int swq, int swr)
{
  __shared__ __align__(16) ushort_t lsA[128 * 64];
  __shared__ __align__(16) ushort_t lsB[128 * 64];
  int bm, bn;
  if (nbn > 0) {
    int bid = blockIdx.x, xcd = bid & 7, slot = bid >> 3;
    int L = (xcd < swr) ? xcd * (swq + 1) + slot
                        : swr * (swq + 1) + (xcd - swr) * swq + slot;
    bm = L / nbn; bn = L - bm * nbn;
  } else {
    bm = blockIdx.x; bn = blockIdx.y;
  }
  int m0 = bm * 128, n0 = bn * 128;
  int tid = threadIdx.x, lane = tid & 63, w = tid >> 6;
  int wr = w >> 1, wc = w & 1;
  int l15 = lane & 15, lk = lane >> 4;
  f32x4 acc[4][4];
  #pragma unroll
  for (int i = 0; i < 4; ++i)
    #pragma unroll
    for (int j = 0; j < 4; ++j)
      #pragma unroll
      for (int r = 0; r < 4; ++r) acc[i][j][r] = 0.f;

  int r_in = lane >> 3, p = lane & 7;
  for (int kt = 0; kt < KT; ++kt) {
    __syncthreads();
    #pragma unroll
    for (int i = 0; i < 4; ++i) {
      int seg = w * 4 + i;
      int row = seg * 8 + r_in;
      int sl = p ^ (row & 7);
      int m = m0 + row;
      if (m < M)
        __builtin_amdgcn_global_load_lds(
            (gu32*)(A + (size_t)m * lda + kt * 64 + sl * 8),
            (lu32*)(lsA + seg * 512), 16, 0, 0);
      int n = n0 + row;
      if (n < N)
        __builtin_amdgcn_global_load_lds(
            (gu32*)(B + (size_t)n * ldb + kt * 64 + sl * 8),
            (lu32*)(lsB + seg * 512), 16, 0, 0);
    }
    __syncthreads();
    #pragma unroll
    for (int ks = 0; ks < 2; ++ks) {
      short8 af[4], bfv[4];
      #pragma unroll
      for (int f = 0; f < 4; ++f) {
        int row = wr * 64 + f * 16 + l15;
        af[f] = *reinterpret_cast<const short8*>(
            &lsA[row * 64 + (((ks * 4 + lk) ^ (row & 7)) << 3)]);
        int rowb = wc * 64 + f * 16 + l15;
        bfv[f] = *reinterpret_cast<const short8*>(
            &lsB[rowb * 64 + (((ks * 4 + lk) ^ (rowb & 7)) << 3)]);
      }
      #pragma unroll
      for (int fm = 0; fm < 4; ++fm)
        #pragma unroll
        for (int fn = 0; fn < 4; ++fn)
          acc[fm][fn] = __builtin_amdgcn_mfma_f32_16x16x32_bf16(af[fm], bfv[fn], acc[fm][fn], 0, 0, 0);
    }
  }
  #pragma unroll
  for (int fm = 0; fm < 4; ++fm)
    #pragma unroll
    for (int fn = 0; fn < 4; ++fn)
      #pragma unroll
      for (int r = 0; r < 4; ++r) {
        int m = m0 + wr * 64 + fm * 16 + lk * 4 + r;
        int n = n0 + wc * 64 + fn * 16 + l15;
        if (m < M && n < N) {
          float v = acc[fm][fn][r] + bias[n];
          v = fmaxf(v, 0.f);
          if (EPI == 2) v += resid[(size_t)m * ldc + n];
          C[(size_t)m * ldc + n] = v;
        }
      }
}

// ---------------- fused biLSTM recurrence ----------------

__global__ __launch_bounds__(256) void lstm_recur(
    const ushort_t* __restrict__ pre,    // [20][250][50][256] bf16
    const ushort_t* __restrict__ whh,    // [2][400][128] bf16 (k-padded)
    ushort_t* __restrict__ hcat)         // [4000][256] bf16
{
  __shared__ __align__(16) ushort_t gx[25 * 256];     // gate exchange
  __shared__ __align__(16) ushort_t h_lds[16 * 128];  // h, swizzled slot^row

  int dir = blockIdx.y;
  int c = blockIdx.x;                   // seq chunk (16 seqs)
  int tid = threadIdx.x, lane = tid & 63, w = tid >> 6;
  int s = lane & 15, lk = lane >> 4;

  short8 wf[7][4];
  #pragma unroll
  for (int qi = 0; qi < 7; ++qi) {
    int q = w + qi * 4;
    if (q < 25) {
      const ushort_t* wp = whh + ((size_t)dir * 400 + q * 16 + s) * 128;
      #pragma unroll
      for (int ks = 0; ks < 4; ++ks)
        wf[qi][ks] = *reinterpret_cast<const short8*>(wp + ks * 32 + lk * 8);
    }
  }
  for (int e = tid; e < 1024; e += 256)
    *reinterpret_cast<u32*>(&h_lds[e * 2]) = 0u;

  float cst[2][4];
  #pragma unroll
  for (int g = 0; g < 2; ++g)
    #pragma unroll
    for (int r = 0; r < 4; ++r) cst[g][r] = 0.f;

  uint2 pvA[7], pvB[7];
  {
    int tt0 = dir ? 19 : 0;
    const ushort_t* pb = pre + ((((size_t)tt0 * 250 + c) * 50 + dir * 25) << 8);
    #pragma unroll
    for (int qi = 0; qi < 7; ++qi) {
      int q = w + qi * 4;
      if (q < 25) pvA[qi] = *reinterpret_cast<const uint2*>(pb + (q << 8) + s * 16 + lk * 4);
    }
  }
  __syncthreads();

  auto step = [&](uint2 (&pvc)[7], uint2 (&pvn)[7], int t) {
    f32x4 acc[7];
    #pragma unroll
    for (int qi = 0; qi < 7; ++qi)
      #pragma unroll
      for (int r = 0; r < 4; ++r) acc[qi][r] = 0.f;
    #pragma unroll
    for (int ks = 0; ks < 4; ++ks) {
      short8 af = *reinterpret_cast<const short8*>(
          &h_lds[s * 128 + (((ks * 4 + lk) ^ s) << 3)]);
      #pragma unroll
      for (int qi = 0; qi < 7; ++qi)
        if (w + qi * 4 < 25)
          acc[qi] = __builtin_amdgcn_mfma_f32_16x16x32_bf16(af, wf[qi][ks], acc[qi], 0, 0, 0);
    }
    #pragma unroll
    for (int qi = 0; qi < 7; ++qi)
      if (w + qi * 4 < 25) {
        acc[qi][0] += bflo(pvc[qi].x); acc[qi][1] += bfhi(pvc[qi].x);
        acc[qi][2] += bflo(pvc[qi].y); acc[qi][3] += bfhi(pvc[qi].y);
      }
    if (t + 1 < 20) {
      int tn = dir ? 19 - (t + 1) : (t + 1);
      const ushort_t* pb = pre + ((((size_t)tn * 250 + c) * 50 + dir * 25) << 8);
      #pragma unroll
      for (int qi = 0; qi < 7; ++qi) {
        int q = w + qi * 4;
        if (q < 25) pvn[qi] = *reinterpret_cast<const uint2*>(pb + (q << 8) + s * 16 + lk * 4);
      }
    }
    #pragma unroll
    for (int qi = 0; qi < 7; ++qi) {
      int q = w + qi * 4;
      if (q < 25) {
        ushort4 pk;
        pk.x = f2bf(acc[qi][0]); pk.y = f2bf(acc[qi][1]);
        pk.z = f2bf(acc[qi][2]); pk.w = f2bf(acc[qi][3]);
        *reinterpret_cast<ushort4*>(&gx[(q << 8) + s * 16 + lk * 4]) = pk;
      }
    }
    __syncthreads();
    #pragma unroll
    for (int gd = 0; gd < 2; ++gd) {
      int gi = w + gd * 4;
      if (gi < 7) {
        int j = gi * 16 + s;
        if (j < 100) {
          auto ld2 = [&](int q, int sp) {
            return *reinterpret_cast<const uint2*>(&gx[(q << 8) + sp * 16 + lk * 4]);
          };
          uint2 iv = ld2(gi, s);
          uint2 fv = (s < 12) ? ld2(6 + gi, s + 4) : ld2(7 + gi, s - 12);
          uint2 gv = (s < 8) ? ld2(12 + gi, s + 8) : ld2(13 + gi, s - 8);
          uint2 ov = (s < 4) ? ld2(18 + gi, s + 12) : ld2(19 + gi, s - 4);
          float ia[4] = {bflo(iv.x), bfhi(iv.x), bflo(iv.y), bfhi(iv.y)};
          float fa[4] = {bflo(fv.x), bfhi(fv.x), bflo(fv.y), bfhi(fv.y)};
          float ga[4] = {bflo(gv.x), bfhi(gv.x), bflo(gv.y), bfhi(gv.y)};
          float oa[4] = {bflo(ov.x), bfhi(ov.x), bflo(ov.y), bfhi(ov.y)};
          #pragma unroll
          for (int r = 0; r < 4; ++r) {
            float cc = sigm(fa[r]) * cst[gd][r] + sigm(ia[r]) * tanh_f(ga[r]);
            cst[gd][r] = cc;
            int row = lk * 4 + r;
            h_lds[row * 128 + (((j >> 3) ^ row) << 3) + (j & 7)] =
                f2bf(sigm(oa[r]) * tanh_f(cc));
          }
        }
      }
    }
    __syncthreads();
  };

  #pragma unroll 1
  for (int tp = 0; tp < 10; ++tp) {
    step(pvA, pvB, 2 * tp);
    step(pvB, pvA, 2 * tp + 1);
  }

  {
    int row = tid >> 4, sl = tid & 15;
    uint2 v = *reinterpret_cast<const uint2*>(&h_lds[row * 128 + ((sl ^ row) << 3)]);
    *reinterpret_cast<uint2*>(&hcat[(size_t)(c * 16 + row) * 256 + dir * 128 + sl * 8]) = v;
  }
}

// ---------------- small f32 kernels ----------------

__global__ void rowdot(const float* __restrict__ X, int ld, const float* __restrict__ w,
                       const float* __restrict__ b0, float* __restrict__ out, int nrows) {
  int row = blockIdx.x;
  if (row >= nrows) return;
  int lane = threadIdx.x;   // 64
  const float* x = X + (size_t)row * ld;
  float s = 0.f;
  for (int k = lane; k < 768; k += 64) s += x[k] * w[k];
  for (int off = 32; off; off >>= 1) s += __shfl_down(s, off);
  if (lane == 0) out[row] = s + b0[0];
}

template <int TRANSB, int EPI>
__global__ __launch_bounds__(256) void bgemm(
    const float* __restrict__ A, long long sA, int lda,
    const float* __restrict__ B, long long sB, int ldb,
    float* __restrict__ C, long long sC, int ldc,
    int M, int N, int K,
    const float* __restrict__ p1, const float* __restrict__ p2,
    const int* __restrict__ amask, const int* __restrict__ cmask,
    const float* __restrict__ w3v) {
  int b = blockIdx.z;
  __shared__ float As[32][33], Bs[32][33];
  int tx = threadIdx.x, ty = threadIdx.y;
  int t = ty * 16 + tx;
  int n0 = blockIdx.x * 32, m0 = blockIdx.y * 32;
  const float* Ab = A + (size_t)b * sA;
  const float* Bb = B + (size_t)b * sB;
  float c00 = 0, c01 = 0, c10 = 0, c11 = 0;
  for (int k0 = 0; k0 < K; k0 += 32) {
    __syncthreads();
    #pragma unroll
    for (int i = 0; i < 4; ++i) {
      int e = t + i * 256;
      int r = e >> 5, q = e & 31;
      {
        int m = m0 + r, k = k0 + q;
        float av = (m < M && k < K) ? Ab[(size_t)m * lda + k] : 0.f;
        if (EPI == 1) av *= w3v[k < K ? k : 0];   // fused W3*bert
        As[r][q] = av;
      }
      if (TRANSB) {
        int n = n0 + r, k = k0 + q;
        Bs[q][r] = (n < N && k < K) ? Bb[(size_t)n * ldb + k] : 0.f;
      } else {
        int k = k0 + r, n = n0 + q;
        Bs[r][q] = (k < K && n < N) ? Bb[(size_t)k * ldb + n] : 0.f;
      }
    }
    __syncthreads();
    #pragma unroll 8
    for (int k = 0; k < 32; ++k) {
      float a0 = As[ty][k], a1 = As[ty + 16][k];
      float b0 = Bs[k][tx], b1 = Bs[k][tx + 16];
      c00 += a0 * b0; c01 += a0 * b1;
      c10 += a1 * b0; c11 += a1 * b1;
    }
  }
  float cc[2][2] = {{c00, c01}, {c10, c11}};
  #pragma unroll
  for (int i = 0; i < 2; ++i)
    #pragma unroll
    for (int j = 0; j < 2; ++j) {
      int m = m0 + ty + 16 * i, n = n0 + tx + 16 * j;
      if (m < M && n < N) {
        float v = cc[i][j];
        if (EPI == 1) {
          v += p1[b * M + m] + p2[b * N + n];
          v += (1.f - (float)amask[b * M + m]) * -10000.f;
          v += (1.f - (float)cmask[b * N + n]) * -10000.f;
        }
        C[(size_t)b * sC + (size_t)m * ldc + n] = v;
      }
    }
}

__global__ void softmax_p(const float* __restrict__ total, float* __restrict__ out) {
  int row = blockIdx.x;   // 5120
  int lane = threadIdx.x; // 64
  const float* x = total + (size_t)row * 100;
  float e0 = x[lane];
  bool has1 = (lane + 64) < 100;
  float e1 = has1 ? x[lane + 64] : -3.4e38f;
  float m = fmaxf(e0, e1);
  for (int off = 32; off; off >>= 1) m = fmaxf(m, __shfl_xor(m, off));
  float s0 = expf(e0 - m), s1 = has1 ? expf(e1 - m) : 0.f;
  float s = s0 + s1;
  for (int off = 32; off; off >>= 1) s += __shfl_xor(s, off);
  float inv = 1.f / s;
  float* o = out + (size_t)row * 100;
  o[lane] = s0 * inv;
  if (has1) o[lane + 64] = s1 * inv;
}

__global__ void softmax_s(const float* __restrict__ total, float* __restrict__ out) {
  int col = blockIdx.x;   // 4000
  int b = col / 100, p = col - b * 100;
  int lane = threadIdx.x;
  const float* base = total + (size_t)b * 12800 + p;
  float e0 = base[lane * 100], e1 = base[(lane + 64) * 100];
  float m = fmaxf(e0, e1);
  for (int off = 32; off; off >>= 1) m = fmaxf(m, __shfl_xor(m, off));
  float s0 = expf(e0 - m), s1 = expf(e1 - m);
  float s = s0 + s1;
  for (int off = 32; off; off >>= 1) s += __shfl_xor(s, off);
  float inv = 1.f / s;
  float* o = out + (size_t)b * 12800 + p;
  o[lane * 100] = s0 * inv;
  o[(lane + 64) * 100] = s1 * inv;
}

__global__ void catk(const float* __restrict__ bert, const float* __restrict__ wcs,
                     const float* __restrict__ wctx, ushort_t* __restrict__ cat) {
  const int TOT = 5120 * 3072;
  for (int i = blockIdx.x * 256 + threadIdx.x; i < TOT; i += gridDim.x * 256) {
    int row = i / 3072, col = i - row * 3072;
    int seg = col / 768;
    int h = col - seg * 768;
    size_t e = (size_t)row * 768 + h;
    float v;
    if (seg == 0) v = bert[e];
    else if (seg == 1) v = wcs[e];
    else if (seg == 2) v = bert[e] * wcs[e];
    else v = bert[e] * wctx[e];
    cat[i] = f2bf(v);
  }
}

__global__ __launch_bounds__(256) void layernorm(float* __restrict__ X,
                                                 const float* __restrict__ w,
                                                 const float* __restrict__ bta) {
  int row = blockIdx.x;   // 5120
  float* x = X + (size_t)row * 768;
  int t = threadIdx.x;
  float v[3];
  float s = 0.f;
  #pragma unroll
  for (int i = 0; i < 3; ++i) { v[i] = x[t + 256 * i]; s += v[i]; }
  __shared__ float red[256];
  red[t] = s; __syncthreads();
  for (int off = 128; off; off >>= 1) { if (t < off) red[t] += red[t + off]; __syncthreads(); }
  float mean = red[0] * (1.f / 768.f);
  __syncthreads();
  float q = 0.f;
  #pragma unroll
  for (int i = 0; i < 3; ++i) { float d = v[i] - mean; q += d * d; }
  red[t] = q; __syncthreads();
  for (int off = 128; off; off >>= 1) { if (t < off) red[t] += red[t + off]; __syncthreads(); }
  float inv = rsqrtf(red[0] * (1.f / 768.f) + 1e-12f);
  #pragma unroll
  for (int i = 0; i < 3; ++i) {
    int k = t + 256 * i;
    x[k] = w[k] * ((v[i] - mean) * inv) + bta[k];
  }
}

// ---------------- host orchestration ----------------

extern "C" void kernel_launch(void* const* d_in, const int* in_sizes, int n_in,
                              void* d_out, int out_size, void* d_ws, size_t ws_size,
                              hipStream_t stream) {
  (void)in_sizes; (void)n_in; (void)out_size; (void)ws_size;
  const float* bert  = (const float*)d_in[0];
  const float* cmn   = (const float*)d_in[1];
  const int*   amask = (const int*)d_in[2];
  const int*   cmask = (const int*)d_in[3];
  const float* Wih_f = (const float*)d_in[8];
  const float* Whh_f = (const float*)d_in[9];
  const float* bih_f = (const float*)d_in[10];
  const float* bhh_f = (const float*)d_in[11];
  const float* Wih_b = (const float*)d_in[12];
  const float* Whh_b = (const float*)d_in[13];
  const float* bih_b = (const float*)d_in[14];
  const float* bhh_b = (const float*)d_in[15];
  const float* projW = (const float*)d_in[16];
  const float* projb = (const float*)d_in[17];
  const float* W1w   = (const float*)d_in[18];
  const float* W1b   = (const float*)d_in[19];
  const float* W2w   = (const float*)d_in[20];
  const float* W2b   = (const float*)d_in[21];
  const float* W3    = (const float*)d_in[22];
  const float* attpW = (const float*)d_in[23];
  const float* attpb = (const float*)d_in[24];
  const float* lnw   = (const float*)d_in[25];
  const float* lnb   = (const float*)d_in[26];

  char* base = (char*)d_ws;
  size_t off = 0;
  auto alloc = [&](size_t bytes) -> char* {
    char* r = base + off;
    off += (bytes + 255) & ~(size_t)255;
    return r;
  };
  ushort_t* wihcat   = (ushort_t*)alloc(800 * 768 * 2);
  ushort_t* whhcat   = (ushort_t*)alloc(800 * 128 * 2);
  float*    biascat  = (float*)alloc(800 * 4);
  ushort_t* projw_bf = (ushort_t*)alloc(768 * 256 * 2);
  ushort_t* attpw_bf = (ushort_t*)alloc(768 * 3072 * 2);
  ushort_t* hcat     = (ushort_t*)alloc(4000 * 256 * 2);
  float*    cs       = (float*)alloc((size_t)4000 * 768 * 4);
  float*    part1    = (float*)alloc(5120 * 4);
  float*    part2    = (float*)alloc(4000 * 4);
  float*    total_s  = (float*)alloc((size_t)40 * 128 * 100 * 4);
  float*    cs_att   = (float*)alloc((size_t)40 * 128 * 100 * 4);
  float*    ctx_att  = (float*)alloc((size_t)40 * 128 * 100 * 4);
  float*    probs    = (float*)alloc((size_t)40 * 128 * 128 * 4);
  float*    wcs      = (float*)alloc((size_t)40 * 128 * 768 * 4);
  float*    wctx     = (float*)alloc((size_t)40 * 128 * 768 * 4);
  ushort_t* cat      = (ushort_t*)alloc((size_t)5120 * 3072 * 2);
  ushort_t* pre      = (ushort_t*)alloc((size_t)20 * 250 * 50 * 256 * 2);  // 128 MB bf16

  prep_weights<<<512, 256, 0, stream>>>(Wih_f, Wih_b, Whh_f, Whh_b, bih_f, bhh_f, bih_b, bhh_b,
                                        projW, attpW, wihcat, whhcat, biascat, projw_bf, attpw_bf);

  // pre = x @ Wih^T + (bih+bhh), fused f32->bf16 conversion, DMA-free K-loop
  gemm_pre<<<4375, 256, 0, stream>>>(cmn, wihcat, biascat, pre);
  // fused 20-step bidirectional recurrence
  lstm_recur<<<dim3(250, 2), 256, 0, stream>>>(pre, whhcat, hcat);

  // cs = relu(hcat @ projW^T + projb)  [4000][768]
  gemm128<1><<<dim3(32, 6), 256, 0, stream>>>(hcat, 256, projw_bf, 256, 4000, 768, 4,
                                              projb, nullptr, cs, 768, 0, 0, 0);
  rowdot<<<5120, 64, 0, stream>>>(bert, 768, W1w, W1b, part1, 5120);
  rowdot<<<4000, 64, 0, stream>>>(cs, 768, W2w, W2b, part2, 4000);
  // total[b,s,p] = part1 + part2 + (W3*bert)@cs^T + masks  (W3 fused into A-load)
  bgemm<1, 1><<<dim3(4, 4, 40), dim3(16, 16), 0, stream>>>(
      bert, 98304LL, 768, cs, 76800LL, 768, total_s, 12800LL, 100,
      128, 100, 768, part1, part2, amask, cmask, W3);
  softmax_p<<<5120, 64, 0, stream>>>(total_s, cs_att);
  softmax_s<<<4000, 64, 0, stream>>>(total_s, ctx_att);
  // weight_cs = cs_att @ cs
  bgemm<0, 0><<<dim3(24, 4, 40), dim3(16, 16), 0, stream>>>(
      cs_att, 12800LL, 100, cs, 76800LL, 768, wcs, 98304LL, 768,
      128, 768, 100, nullptr, nullptr, nullptr, nullptr, nullptr);
  // probs = cs_att @ ctx_att^T
  bgemm<1, 0><<<dim3(4, 4, 40), dim3(16, 16), 0, stream>>>(
      cs_att, 12800LL, 100, ctx_att, 12800LL, 100, probs, 16384LL, 128,
      128, 128, 100, nullptr, nullptr, nullptr, nullptr, nullptr);
  // weighted_context = probs @ bert
  bgemm<0, 0><<<dim3(24, 4, 40), dim3(16, 16), 0, stream>>>(
      probs, 16384LL, 128, bert, 98304LL, 768, wctx, 98304LL, 768,
      128, 768, 128, nullptr, nullptr, nullptr, nullptr, nullptr);
  catk<<<2048, 256, 0, stream>>>(bert, wcs, wctx, cat);
  // x = relu(cat @ attpW^T + attpb) + bert  -> d_out, then LN in place
  gemm128<2><<<240, 256, 0, stream>>>(cat, 3072, attpw_bf, 3072, 5120, 768, 48,
                                      attpb, bert, (float*)d_out, 768, 6, 30, 0);
  layernorm<<<5120, 256, 0, stream>>>((float*)d_out, lnw, lnb);
}

// Round 7
// 649.719 us; speedup vs baseline: 1.3856x; 1.3856x over previous
//
#include <hip/hip_runtime.h>

// QANet attention layer on MI355X (gfx950).
// B=40,S=128,H=768, NP=100, PL=20, HID=100, N=4000 sequences.
// Round 7: revert pre-GEMM to the measured-fastest r3 structure (separate
// f32->bf16 convert kernel + global_load_lds DMA GEMM, 3.44 TB/s) and add the
// bijective XCD-chunked grid (proven in r4/r5 to cut FETCH 425->140 MB).
// Reg-staged fused conversion (r4-r6) capped at ~1.1 TB/s; abandoned.

typedef unsigned short ushort_t;
typedef unsigned int u32;
typedef __attribute__((ext_vector_type(8))) short short8;
typedef __attribute__((ext_vector_type(4))) float f32x4;
typedef __attribute__((address_space(1))) const u32 gu32;
typedef __attribute__((address_space(3))) u32 lu32;

__device__ __forceinline__ ushort_t f2bf(float f) {
  u32 x = __builtin_bit_cast(u32, f);
  u32 r = (x + 0x7fffu + ((x >> 16) & 1u)) >> 16;
  return (ushort_t)r;
}
__device__ __forceinline__ float bflo(u32 u) { return __builtin_bit_cast(float, u << 16); }
__device__ __forceinline__ float bfhi(u32 u) { return __builtin_bit_cast(float, u & 0xffff0000u); }
__device__ __forceinline__ u32 cvtpk(float lo, float hi) {
  u32 r;
  asm("v_cvt_pk_bf16_f32 %0, %1, %2" : "=v"(r) : "v"(lo), "v"(hi));
  return r;
}

__device__ __forceinline__ float sigm(float x) { return 1.f / (1.f + __expf(-x)); }
__device__ __forceinline__ float tanh_f(float x) { return 1.f - 2.f / (__expf(2.f * x) + 1.f); }

// ---------------- prep / convert kernels ----------------

__global__ void prep_weights(const float* __restrict__ Wih_f, const float* __restrict__ Wih_b,
                             const float* __restrict__ Whh_f, const float* __restrict__ Whh_b,
                             const float* __restrict__ bih_f, const float* __restrict__ bhh_f,
                             const float* __restrict__ bih_b, const float* __restrict__ bhh_b,
                             const float* __restrict__ projW, const float* __restrict__ attpW,
                             ushort_t* __restrict__ wihcat, ushort_t* __restrict__ whhcat,
                             float* __restrict__ biascat, ushort_t* __restrict__ projw_bf,
                             ushort_t* __restrict__ attpw_bf) {
  const int TOT = 614400 + 102400 + 800 + 196608 + 2359296;
  for (int idx = blockIdx.x * 256 + threadIdx.x; idx < TOT; idx += gridDim.x * 256) {
    if (idx < 614400) {                       // Wih cat [800][768]
      int g = idx / 768, k = idx % 768;
      float v = g < 400 ? Wih_f[g * 768 + k] : Wih_b[(g - 400) * 768 + k];
      wihcat[idx] = f2bf(v);
    } else if (idx < 716800) {                // Whh cat padded [2][400][128]
      int e = idx - 614400; int g = e / 128, j = e % 128;
      float v = 0.f;
      if (j < 100) v = g < 400 ? Whh_f[g * 100 + j] : Whh_b[(g - 400) * 100 + j];
      whhcat[e] = f2bf(v);
    } else if (idx < 717600) {                // bias cat [800]
      int g = idx - 716800;
      biascat[g] = g < 400 ? bih_f[g] + bhh_f[g] : bih_b[g - 400] + bhh_b[g - 400];
    } else if (idx < 914208) {                // projW padded [768][256]
      int e = idx - 717600; int o = e / 256, j = e % 256;
      float v = 0.f;
      if (j < 100) v = projW[o * 200 + j];
      else if (j >= 128 && j < 228) v = projW[o * 200 + 100 + (j - 128)];
      projw_bf[e] = f2bf(v);
    } else {                                  // attpW [768][3072]
      int e = idx - 914208;
      attpw_bf[e] = f2bf(attpW[e]);
    }
  }
}

// x [4000][20][768] f32 -> x_bf [20][4000][768] bf16 (t-major)
__global__ void convert_x_t(const float4* __restrict__ x4, ushort_t* __restrict__ xb) {
  for (int i = blockIdx.x * 256 + threadIdx.x; i < 15360000; i += gridDim.x * 256) {
    int seq = i / 3840;              // 20*192 float4 per seq
    int rem = i - seq * 3840;
    int t = rem / 192;
    int k4 = rem - t * 192;
    float4 v = x4[i];
    ushort4 o;
    o.x = f2bf(v.x); o.y = f2bf(v.y); o.z = f2bf(v.z); o.w = f2bf(v.w);
    *reinterpret_cast<ushort4*>(&xb[((size_t)t * 4000 + seq) * 768 + k4 * 4]) = o;
  }
}

// ---------------- 128x128 MFMA GEMM (global_load_lds) ----------------
// EPI 0: pre-layout store P[t][seqchunk][nq][off] bf16 (+bias), off=s*16+lk*4+r
// EPI 1: relu(v+bias) f32; EPI 2: relu(v+bias)+resid f32.
// nbn>0: linear grid + bijective XCD-chunk swizzle (bn fastest within bm).

template <int EPI>
__global__ __launch_bounds__(256) void gemm128(
    const ushort_t* __restrict__ A, int lda,
    const ushort_t* __restrict__ B, int ldb,
    int M, int N, int KT,
    const float* __restrict__ bias,
    const float* __restrict__ resid,
    float* __restrict__ C, int ldc,
    int nbn, int swq, int swr)
{
  __shared__ __align__(16) ushort_t lsA[128 * 64];
  __shared__ __align__(16) ushort_t lsB[128 * 64];
  int bm, bn;
  if (nbn > 0) {
    int bid = blockIdx.x, xcd = bid & 7, slot = bid >> 3;
    int L = (xcd < swr) ? xcd * (swq + 1) + slot
                        : swr * (swq + 1) + (xcd - swr) * swq + slot;
    bm = L / nbn; bn = L - bm * nbn;
  } else {
    bm = blockIdx.x; bn = blockIdx.y;
  }
  int m0 = bm * 128, n0 = bn * 128;
  int tid = threadIdx.x, lane = tid & 63, w = tid >> 6;
  int wr = w >> 1, wc = w & 1;
  int l15 = lane & 15, lk = lane >> 4;
  f32x4 acc[4][4];
  #pragma unroll
  for (int i = 0; i < 4; ++i)
    #pragma unroll
    for (int j = 0; j < 4; ++j)
      #pragma unroll
      for (int r = 0; r < 4; ++r) acc[i][j][r] = 0.f;

  int r_in = lane >> 3, p = lane & 7;
  for (int kt = 0; kt < KT; ++kt) {
    __syncthreads();
    #pragma unroll
    for (int i = 0; i < 4; ++i) {
      int seg = w * 4 + i;
      int row = seg * 8 + r_in;
      int sl = p ^ (row & 7);
      int m = m0 + row;
      if (m < M)
        __builtin_amdgcn_global_load_lds(
            (gu32*)(A + (size_t)m * lda + kt * 64 + sl * 8),
            (lu32*)(lsA + seg * 512), 16, 0, 0);
      int n = n0 + row;
      if (n < N)
        __builtin_amdgcn_global_load_lds(
            (gu32*)(B + (size_t)n * ldb + kt * 64 + sl * 8),
            (lu32*)(lsB + seg * 512), 16, 0, 0);
    }
    __syncthreads();
    #pragma unroll
    for (int ks = 0; ks < 2; ++ks) {
      short8 af[4], bfv[4];
      #pragma unroll
      for (int f = 0; f < 4; ++f) {
        int row = wr * 64 + f * 16 + l15;
        af[f] = *reinterpret_cast<const short8*>(
            &lsA[row * 64 + (((ks * 4 + lk) ^ (row & 7)) << 3)]);
        int rowb = wc * 64 + f * 16 + l15;
        bfv[f] = *reinterpret_cast<const short8*>(
            &lsB[rowb * 64 + (((ks * 4 + lk) ^ (rowb & 7)) << 3)]);
      }
      #pragma unroll
      for (int fm = 0; fm < 4; ++fm)
        #pragma unroll
        for (int fn = 0; fn < 4; ++fn)
          acc[fm][fn] = __builtin_amdgcn_mfma_f32_16x16x32_bf16(af[fm], bfv[fn], acc[fm][fn], 0, 0, 0);
    }
  }
  if (EPI == 0) {
    // m = t*4000 + seq (t-major); 16-row frags never straddle t (4000%16==0)
    ushort_t* P = (ushort_t*)C;
    #pragma unroll
    for (int fm = 0; fm < 4; ++fm) {
      int mb = m0 + wr * 64 + fm * 16;
      int t = mb / 4000;
      int sq = mb - t * 4000;
      int cch = sq >> 4;
      #pragma unroll
      for (int fn = 0; fn < 4; ++fn) {
        int nb = n0 + wc * 64 + fn * 16;
        if (nb < N) {
          int nl = nb < 400 ? nb : nb - 400;
          int nq = (nb < 400 ? 0 : 25) + (nl >> 4);
          float bsv = bias[nb + l15];
          uint2 pk;
          pk.x = cvtpk(acc[fm][fn][0] + bsv, acc[fm][fn][1] + bsv);
          pk.y = cvtpk(acc[fm][fn][2] + bsv, acc[fm][fn][3] + bsv);
          *reinterpret_cast<uint2*>(
              &P[((((size_t)t * 250 + cch) * 50 + nq) << 8) + l15 * 16 + lk * 4]) = pk;
        }
      }
    }
  } else {
    #pragma unroll
    for (int fm = 0; fm < 4; ++fm)
      #pragma unroll
      for (int fn = 0; fn < 4; ++fn)
        #pragma unroll
        for (int r = 0; r < 4; ++r) {
          int m = m0 + wr * 64 + fm * 16 + lk * 4 + r;
          int n = n0 + wc * 64 + fn * 16 + l15;
          if (m < M && n < N) {
            float v = acc[fm][fn][r] + bias[n];
            v = fmaxf(v, 0.f);
            if (EPI == 2) v += resid[(size_t)m * ldc + n];
            C[(size_t)m * ldc + n] = v;
          }
        }
  }
}

// ---------------- fused biLSTM recurrence ----------------

__global__ __launch_bounds__(256) void lstm_recur(
    const ushort_t* __restrict__ pre,    // [20][250][50][256] bf16
    const ushort_t* __restrict__ whh,    // [2][400][128] bf16 (k-padded)
    ushort_t* __restrict__ hcat)         // [4000][256] bf16
{
  __shared__ __align__(16) ushort_t gx[25 * 256];     // gate exchange
  __shared__ __align__(16) ushort_t h_lds[16 * 128];  // h, swizzled slot^row

  int dir = blockIdx.y;
  int c = blockIdx.x;                   // seq chunk (16 seqs)
  int tid = threadIdx.x, lane = tid & 63, w = tid >> 6;
  int s = lane & 15, lk = lane >> 4;

  short8 wf[7][4];
  #pragma unroll
  for (int qi = 0; qi < 7; ++qi) {
    int q = w + qi * 4;
    if (q < 25) {
      const ushort_t* wp = whh + ((size_t)dir * 400 + q * 16 + s) * 128;
      #pragma unroll
      for (int ks = 0; ks < 4; ++ks)
        wf[qi][ks] = *reinterpret_cast<const short8*>(wp + ks * 32 + lk * 8);
    }
  }
  for (int e = tid; e < 1024; e += 256)
    *reinterpret_cast<u32*>(&h_lds[e * 2]) = 0u;

  float cst[2][4];
  #pragma unroll
  for (int g = 0; g < 2; ++g)
    #pragma unroll
    for (int r = 0; r < 4; ++r) cst[g][r] = 0.f;

  uint2 pvA[7], pvB[7];
  {
    int tt0 = dir ? 19 : 0;
    const ushort_t* pb = pre + ((((size_t)tt0 * 250 + c) * 50 + dir * 25) << 8);
    #pragma unroll
    for (int qi = 0; qi < 7; ++qi) {
      int q = w + qi * 4;
      if (q < 25) pvA[qi] = *reinterpret_cast<const uint2*>(pb + (q << 8) + s * 16 + lk * 4);
    }
  }
  __syncthreads();

  auto step = [&](uint2 (&pvc)[7], uint2 (&pvn)[7], int t) {
    f32x4 acc[7];
    #pragma unroll
    for (int qi = 0; qi < 7; ++qi)
      #pragma unroll
      for (int r = 0; r < 4; ++r) acc[qi][r] = 0.f;
    #pragma unroll
    for (int ks = 0; ks < 4; ++ks) {
      short8 af = *reinterpret_cast<const short8*>(
          &h_lds[s * 128 + (((ks * 4 + lk) ^ s) << 3)]);
      #pragma unroll
      for (int qi = 0; qi < 7; ++qi)
        if (w + qi * 4 < 25)
          acc[qi] = __builtin_amdgcn_mfma_f32_16x16x32_bf16(af, wf[qi][ks], acc[qi], 0, 0, 0);
    }
    #pragma unroll
    for (int qi = 0; qi < 7; ++qi)
      if (w + qi * 4 < 25) {
        acc[qi][0] += bflo(pvc[qi].x); acc[qi][1] += bfhi(pvc[qi].x);
        acc[qi][2] += bflo(pvc[qi].y); acc[qi][3] += bfhi(pvc[qi].y);
      }
    if (t + 1 < 20) {
      int tn = dir ? 19 - (t + 1) : (t + 1);
      const ushort_t* pb = pre + ((((size_t)tn * 250 + c) * 50 + dir * 25) << 8);
      #pragma unroll
      for (int qi = 0; qi < 7; ++qi) {
        int q = w + qi * 4;
        if (q < 25) pvn[qi] = *reinterpret_cast<const uint2*>(pb + (q << 8) + s * 16 + lk * 4);
      }
    }
    #pragma unroll
    for (int qi = 0; qi < 7; ++qi) {
      int q = w + qi * 4;
      if (q < 25) {
        ushort4 pk;
        pk.x = f2bf(acc[qi][0]); pk.y = f2bf(acc[qi][1]);
        pk.z = f2bf(acc[qi][2]); pk.w = f2bf(acc[qi][3]);
        *reinterpret_cast<ushort4*>(&gx[(q << 8) + s * 16 + lk * 4]) = pk;
      }
    }
    __syncthreads();
    #pragma unroll
    for (int gd = 0; gd < 2; ++gd) {
      int gi = w + gd * 4;
      if (gi < 7) {
        int j = gi * 16 + s;
        if (j < 100) {
          auto ld2 = [&](int q, int sp) {
            return *reinterpret_cast<const uint2*>(&gx[(q << 8) + sp * 16 + lk * 4]);
          };
          uint2 iv = ld2(gi, s);
          uint2 fv = (s < 12) ? ld2(6 + gi, s + 4) : ld2(7 + gi, s - 12);
          uint2 gv = (s < 8) ? ld2(12 + gi, s + 8) : ld2(13 + gi, s - 8);
          uint2 ov = (s < 4) ? ld2(18 + gi, s + 12) : ld2(19 + gi, s - 4);
          float ia[4] = {bflo(iv.x), bfhi(iv.x), bflo(iv.y), bfhi(iv.y)};
          float fa[4] = {bflo(fv.x), bfhi(fv.x), bflo(fv.y), bfhi(fv.y)};
          float ga[4] = {bflo(gv.x), bfhi(gv.x), bflo(gv.y), bfhi(gv.y)};
          float oa[4] = {bflo(ov.x), bfhi(ov.x), bflo(ov.y), bfhi(ov.y)};
          #pragma unroll
          for (int r = 0; r < 4; ++r) {
            float cc = sigm(fa[r]) * cst[gd][r] + sigm(ia[r]) * tanh_f(ga[r]);
            cst[gd][r] = cc;
            int row = lk * 4 + r;
            h_lds[row * 128 + (((j >> 3) ^ row) << 3) + (j & 7)] =
                f2bf(sigm(oa[r]) * tanh_f(cc));
          }
        }
      }
    }
    __syncthreads();
  };

  #pragma unroll 1
  for (int tp = 0; tp < 10; ++tp) {
    step(pvA, pvB, 2 * tp);
    step(pvB, pvA, 2 * tp + 1);
  }

  {
    int row = tid >> 4, sl = tid & 15;
    uint2 v = *reinterpret_cast<const uint2*>(&h_lds[row * 128 + ((sl ^ row) << 3)]);
    *reinterpret_cast<uint2*>(&hcat[(size_t)(c * 16 + row) * 256 + dir * 128 + sl * 8]) = v;
  }
}

// ---------------- small f32 kernels ----------------

__global__ void rowdot(const float* __restrict__ X, int ld, const float* __restrict__ w,
                       const float* __restrict__ b0, float* __restrict__ out, int nrows) {
  int row = blockIdx.x;
  if (row >= nrows) return;
  int lane = threadIdx.x;   // 64
  const float* x = X + (size_t)row * ld;
  float s = 0.f;
  for (int k = lane; k < 768; k += 64) s += x[k] * w[k];
  for (int off = 32; off; off >>= 1) s += __shfl_down(s, off);
  if (lane == 0) out[row] = s + b0[0];
}

template <int TRANSB, int EPI>
__global__ __launch_bounds__(256) void bgemm(
    const float* __restrict__ A, long long sA, int lda,
    const float* __restrict__ B, long long sB, int ldb,
    float* __restrict__ C, long long sC, int ldc,
    int M, int N, int K,
    const float* __restrict__ p1, const float* __restrict__ p2,
    const int* __restrict__ amask, const int* __restrict__ cmask,
    const float* __restrict__ w3v) {
  int b = blockIdx.z;
  __shared__ float As[32][33], Bs[32][33];
  int tx = threadIdx.x, ty = threadIdx.y;
  int t = ty * 16 + tx;
  int n0 = blockIdx.x * 32, m0 = blockIdx.y * 32;
  const float* Ab = A + (size_t)b * sA;
  const float* Bb = B + (size_t)b * sB;
  float c00 = 0, c01 = 0, c10 = 0, c11 = 0;
  for (int k0 = 0; k0 < K; k0 += 32) {
    __syncthreads();
    #pragma unroll
    for (int i = 0; i < 4; ++i) {
      int e = t + i * 256;
      int r = e >> 5, q = e & 31;
      {
        int m = m0 + r, k = k0 + q;
        float av = (m < M && k < K) ? Ab[(size_t)m * lda + k] : 0.f;
        if (EPI == 1) av *= w3v[k < K ? k : 0];   // fused W3*bert
        As[r][q] = av;
      }
      if (TRANSB) {
        int n = n0 + r, k = k0 + q;
        Bs[q][r] = (n < N && k < K) ? Bb[(size_t)n * ldb + k] : 0.f;
      } else {
        int k = k0 + r, n = n0 + q;
        Bs[r][q] = (k < K && n < N) ? Bb[(size_t)k * ldb + n] : 0.f;
      }
    }
    __syncthreads();
    #pragma unroll 8
    for (int k = 0; k < 32; ++k) {
      float a0 = As[ty][k], a1 = As[ty + 16][k];
      float b0 = Bs[k][tx], b1 = Bs[k][tx + 16];
      c00 += a0 * b0; c01 += a0 * b1;
      c10 += a1 * b0; c11 += a1 * b1;
    }
  }
  float cc[2][2] = {{c00, c01}, {c10, c11}};
  #pragma unroll
  for (int i = 0; i < 2; ++i)
    #pragma unroll
    for (int j = 0; j < 2; ++j) {
      int m = m0 + ty + 16 * i, n = n0 + tx + 16 * j;
      if (m < M && n < N) {
        float v = cc[i][j];
        if (EPI == 1) {
          v += p1[b * M + m] + p2[b * N + n];
          v += (1.f - (float)amask[b * M + m]) * -10000.f;
          v += (1.f - (float)cmask[b * N + n]) * -10000.f;
        }
        C[(size_t)b * sC + (size_t)m * ldc + n] = v;
      }
    }
}

__global__ void softmax_p(const float* __restrict__ total, float* __restrict__ out) {
  int row = blockIdx.x;   // 5120
  int lane = threadIdx.x; // 64
  const float* x = total + (size_t)row * 100;
  float e0 = x[lane];
  bool has1 = (lane + 64) < 100;
  float e1 = has1 ? x[lane + 64] : -3.4e38f;
  float m = fmaxf(e0, e1);
  for (int off = 32; off; off >>= 1) m = fmaxf(m, __shfl_xor(m, off));
  float s0 = expf(e0 - m), s1 = has1 ? expf(e1 - m) : 0.f;
  float s = s0 + s1;
  for (int off = 32; off; off >>= 1) s += __shfl_xor(s, off);
  float inv = 1.f / s;
  float* o = out + (size_t)row * 100;
  o[lane] = s0 * inv;
  if (has1) o[lane + 64] = s1 * inv;
}

__global__ void softmax_s(const float* __restrict__ total, float* __restrict__ out) {
  int col = blockIdx.x;   // 4000
  int b = col / 100, p = col - b * 100;
  int lane = threadIdx.x;
  const float* base = total + (size_t)b * 12800 + p;
  float e0 = base[lane * 100], e1 = base[(lane + 64) * 100];
  float m = fmaxf(e0, e1);
  for (int off = 32; off; off >>= 1) m = fmaxf(m, __shfl_xor(m, off));
  float s0 = expf(e0 - m), s1 = expf(e1 - m);
  float s = s0 + s1;
  for (int off = 32; off; off >>= 1) s += __shfl_xor(s, off);
  float inv = 1.f / s;
  float* o = out + (size_t)b * 12800 + p;
  o[lane * 100] = s0 * inv;
  o[(lane + 64) * 100] = s1 * inv;
}

__global__ void catk(const float* __restrict__ bert, const float* __restrict__ wcs,
                     const float* __restrict__ wctx, ushort_t* __restrict__ cat) {
  const int TOT = 5120 * 3072;
  for (int i = blockIdx.x * 256 + threadIdx.x; i < TOT; i += gridDim.x * 256) {
    int row = i / 3072, col = i - row * 3072;
    int seg = col / 768;
    int h = col - seg * 768;
    size_t e = (size_t)row * 768 + h;
    float v;
    if (seg == 0) v = bert[e];
    else if (seg == 1) v = wcs[e];
    else if (seg == 2) v = bert[e] * wcs[e];
    else v = bert[e] * wctx[e];
    cat[i] = f2bf(v);
  }
}

__global__ __launch_bounds__(256) void layernorm(float* __restrict__ X,
                                                 const float* __restrict__ w,
                                                 const float* __restrict__ bta) {
  int row = blockIdx.x;   // 5120
  float* x = X + (size_t)row * 768;
  int t = threadIdx.x;
  float v[3];
  float s = 0.f;
  #pragma unroll
  for (int i = 0; i < 3; ++i) { v[i] = x[t + 256 * i]; s += v[i]; }
  __shared__ float red[256];
  red[t] = s; __syncthreads();
  for (int off = 128; off; off >>= 1) { if (t < off) red[t] += red[t + off]; __syncthreads(); }
  float mean = red[0] * (1.f / 768.f);
  __syncthreads();
  float q = 0.f;
  #pragma unroll
  for (int i = 0; i < 3; ++i) { float d = v[i] - mean; q += d * d; }
  red[t] = q; __syncthreads();
  for (int off = 128; off; off >>= 1) { if (t < off) red[t] += red[t + off]; __syncthreads(); }
  float inv = rsqrtf(red[0] * (1.f / 768.f) + 1e-12f);
  #pragma unroll
  for (int i = 0; i < 3; ++i) {
    int k = t + 256 * i;
    x[k] = w[k] * ((v[i] - mean) * inv) + bta[k];
  }
}

// ---------------- host orchestration ----------------

extern "C" void kernel_launch(void* const* d_in, const int* in_sizes, int n_in,
                              void* d_out, int out_size, void* d_ws, size_t ws_size,
                              hipStream_t stream) {
  (void)in_sizes; (void)n_in; (void)out_size; (void)ws_size;
  const float* bert  = (const float*)d_in[0];
  const float* cmn   = (const float*)d_in[1];
  const int*   amask = (const int*)d_in[2];
  const int*   cmask = (const int*)d_in[3];
  const float* Wih_f = (const float*)d_in[8];
  const float* Whh_f = (const float*)d_in[9];
  const float* bih_f = (const float*)d_in[10];
  const float* bhh_f = (const float*)d_in[11];
  const float* Wih_b = (const float*)d_in[12];
  const float* Whh_b = (const float*)d_in[13];
  const float* bih_b = (const float*)d_in[14];
  const float* bhh_b = (const float*)d_in[15];
  const float* projW = (const float*)d_in[16];
  const float* projb = (const float*)d_in[17];
  const float* W1w   = (const float*)d_in[18];
  const float* W1b   = (const float*)d_in[19];
  const float* W2w   = (const float*)d_in[20];
  const float* W2b   = (const float*)d_in[21];
  const float* W3    = (const float*)d_in[22];
  const float* attpW = (const float*)d_in[23];
  const float* attpb = (const float*)d_in[24];
  const float* lnw   = (const float*)d_in[25];
  const float* lnb   = (const float*)d_in[26];

  char* base = (char*)d_ws;
  size_t off = 0;
  auto alloc = [&](size_t bytes) -> char* {
    char* r = base + off;
    off += (bytes + 255) & ~(size_t)255;
    return r;
  };
  ushort_t* wihcat   = (ushort_t*)alloc(800 * 768 * 2);
  ushort_t* whhcat   = (ushort_t*)alloc(800 * 128 * 2);
  float*    biascat  = (float*)alloc(800 * 4);
  ushort_t* projw_bf = (ushort_t*)alloc(768 * 256 * 2);
  ushort_t* attpw_bf = (ushort_t*)alloc(768 * 3072 * 2);
  ushort_t* hcat     = (ushort_t*)alloc(4000 * 256 * 2);
  float*    cs       = (float*)alloc((size_t)4000 * 768 * 4);
  float*    part1    = (float*)alloc(5120 * 4);
  float*    part2    = (float*)alloc(4000 * 4);
  float*    total_s  = (float*)alloc((size_t)40 * 128 * 100 * 4);
  float*    cs_att   = (float*)alloc((size_t)40 * 128 * 100 * 4);
  float*    ctx_att  = (float*)alloc((size_t)40 * 128 * 100 * 4);
  float*    probs    = (float*)alloc((size_t)40 * 128 * 128 * 4);
  float*    wcs      = (float*)alloc((size_t)40 * 128 * 768 * 4);
  float*    wctx     = (float*)alloc((size_t)40 * 128 * 768 * 4);
  ushort_t* cat      = (ushort_t*)alloc((size_t)5120 * 3072 * 2);
  ushort_t* x_bf     = (ushort_t*)alloc((size_t)20 * 4000 * 768 * 2);      // 123 MB t-major
  ushort_t* pre      = (ushort_t*)alloc((size_t)20 * 250 * 50 * 256 * 2);  // 128 MB bf16

  prep_weights<<<512, 256, 0, stream>>>(Wih_f, Wih_b, Whh_f, Whh_b, bih_f, bhh_f, bih_b, bhh_b,
                                        projW, attpW, wihcat, whhcat, biascat, projw_bf, attpw_bf);
  convert_x_t<<<2048, 256, 0, stream>>>((const float4*)cmn, x_bf);

  // pre = x @ Wih^T + (bih+bhh), stored in recurrence lane-layout (bf16);
  // XCD-chunked grid: nwg=4375, q=546, r=7, bn fastest -> A-panel reuse per XCD
  gemm128<0><<<4375, 256, 0, stream>>>(x_bf, 768, wihcat, 768, 80000, 800, 12,
                                       biascat, nullptr, (float*)pre, 0, 7, 546, 7);
  // fused 20-step bidirectional recurrence
  lstm_recur<<<dim3(250, 2), 256, 0, stream>>>(pre, whhcat, hcat);

  // cs = relu(hcat @ projW^T + projb)  [4000][768]
  gemm128<1><<<dim3(32, 6), 256, 0, stream>>>(hcat, 256, projw_bf, 256, 4000, 768, 4,
                                              projb, nullptr, cs, 768, 0, 0, 0);
  rowdot<<<5120, 64, 0, stream>>>(bert, 768, W1w, W1b, part1, 5120);
  rowdot<<<4000, 64, 0, stream>>>(cs, 768, W2w, W2b, part2, 4000);
  // total[b,s,p] = part1 + part2 + (W3*bert)@cs^T + masks  (W3 fused into A-load)
  bgemm<1, 1><<<dim3(4, 4, 40), dim3(16, 16), 0, stream>>>(
      bert, 98304LL, 768, cs, 76800LL, 768, total_s, 12800LL, 100,
      128, 100, 768, part1, part2, amask, cmask, W3);
  softmax_p<<<5120, 64, 0, stream>>>(total_s, cs_att);
  softmax_s<<<4000, 64, 0, stream>>>(total_s, ctx_att);
  // weight_cs = cs_att @ cs
  bgemm<0, 0><<<dim3(24, 4, 40), dim3(16, 16), 0, stream>>>(
      cs_att, 12800LL, 100, cs, 76800LL, 768, wcs, 98304LL, 768,
      128, 768, 100, nullptr, nullptr, nullptr, nullptr, nullptr);
  // probs = cs_att @ ctx_att^T
  bgemm<1, 0><<<dim3(4, 4, 40), dim3(16, 16), 0, stream>>>(
      cs_att, 12800LL, 100, ctx_att, 12800LL, 100, probs, 16384LL, 128,
      128, 128, 100, nullptr, nullptr, nullptr, nullptr, nullptr);
  // weighted_context = probs @ bert
  bgemm<0, 0><<<dim3(24, 4, 40), dim3(16, 16), 0, stream>>>(
      probs, 16384LL, 128, bert, 98304LL, 768, wctx, 98304LL, 768,
      128, 768, 128, nullptr, nullptr, nullptr, nullptr, nullptr);
  catk<<<2048, 256, 0, stream>>>(bert, wcs, wctx, cat);
  // x = relu(cat @ attpW^T + attpb) + bert  -> d_out, then LN in place
  gemm128<2><<<240, 256, 0, stream>>>(cat, 3072, attpw_bf, 3072, 5120, 768, 48,
                                      attpb, bert, (float*)d_out, 768, 6, 30, 0);
  layernorm<<<5120, 256, 0, stream>>>((float*)d_out, lnw, lnb);
}

// Round 8
// 534.562 us; speedup vs baseline: 1.6841x; 1.2154x over previous
//
#include <hip/hip_runtime.h>

// QANet attention layer on MI355X (gfx950).
// B=40,S=128,H=768, NP=100, PL=20, HID=100, N=4000 sequences.
// Round 8: attention chain (total/wcs/probs/wctx) moved from f32 SIMT to
// batched bf16 MFMA (gemm128b). Transposed bf16 operands (csT, bertT) built
// by LDS-tiled transposes; softmax_p/softmax_s merged (writes padded bf16);
// bertW3 folded into bert prep. Pre-GEMM/LSTM unchanged (r7 measured best).

typedef unsigned short ushort_t;
typedef unsigned int u32;
typedef __attribute__((ext_vector_type(8))) short short8;
typedef __attribute__((ext_vector_type(4))) float f32x4;
typedef __attribute__((address_space(1))) const u32 gu32;
typedef __attribute__((address_space(3))) u32 lu32;

__device__ __forceinline__ ushort_t f2bf(float f) {
  u32 x = __builtin_bit_cast(u32, f);
  u32 r = (x + 0x7fffu + ((x >> 16) & 1u)) >> 16;
  return (ushort_t)r;
}
__device__ __forceinline__ float bflo(u32 u) { return __builtin_bit_cast(float, u << 16); }
__device__ __forceinline__ float bfhi(u32 u) { return __builtin_bit_cast(float, u & 0xffff0000u); }
__device__ __forceinline__ u32 cvtpk(float lo, float hi) {
  u32 r;
  asm("v_cvt_pk_bf16_f32 %0, %1, %2" : "=v"(r) : "v"(lo), "v"(hi));
  return r;
}

__device__ __forceinline__ float sigm(float x) { return 1.f / (1.f + __expf(-x)); }
__device__ __forceinline__ float tanh_f(float x) { return 1.f - 2.f / (__expf(2.f * x) + 1.f); }

// ---------------- prep / convert kernels ----------------

__global__ void prep_weights(const float* __restrict__ Wih_f, const float* __restrict__ Wih_b,
                             const float* __restrict__ Whh_f, const float* __restrict__ Whh_b,
                             const float* __restrict__ bih_f, const float* __restrict__ bhh_f,
                             const float* __restrict__ bih_b, const float* __restrict__ bhh_b,
                             const float* __restrict__ projW, const float* __restrict__ attpW,
                             ushort_t* __restrict__ wihcat, ushort_t* __restrict__ whhcat,
                             float* __restrict__ biascat, ushort_t* __restrict__ projw_bf,
                             ushort_t* __restrict__ attpw_bf) {
  const int TOT = 614400 + 102400 + 800 + 196608 + 2359296;
  for (int idx = blockIdx.x * 256 + threadIdx.x; idx < TOT; idx += gridDim.x * 256) {
    if (idx < 614400) {                       // Wih cat [800][768]
      int g = idx / 768, k = idx % 768;
      float v = g < 400 ? Wih_f[g * 768 + k] : Wih_b[(g - 400) * 768 + k];
      wihcat[idx] = f2bf(v);
    } else if (idx < 716800) {                // Whh cat padded [2][400][128]
      int e = idx - 614400; int g = e / 128, j = e % 128;
      float v = 0.f;
      if (j < 100) v = g < 400 ? Whh_f[g * 100 + j] : Whh_b[(g - 400) * 100 + j];
      whhcat[e] = f2bf(v);
    } else if (idx < 717600) {                // bias cat [800]
      int g = idx - 716800;
      biascat[g] = g < 400 ? bih_f[g] + bhh_f[g] : bih_b[g - 400] + bhh_b[g - 400];
    } else if (idx < 914208) {                // projW padded [768][256]
      int e = idx - 717600; int o = e / 256, j = e % 256;
      float v = 0.f;
      if (j < 100) v = projW[o * 200 + j];
      else if (j >= 128 && j < 228) v = projW[o * 200 + 100 + (j - 128)];
      projw_bf[e] = f2bf(v);
    } else {                                  // attpW [768][3072]
      int e = idx - 914208;
      attpw_bf[e] = f2bf(attpW[e]);
    }
  }
}

// x [4000][20][768] f32 -> x_bf [20][4000][768] bf16 (t-major)
__global__ void convert_x_t(const float4* __restrict__ x4, ushort_t* __restrict__ xb) {
  for (int i = blockIdx.x * 256 + threadIdx.x; i < 15360000; i += gridDim.x * 256) {
    int seq = i / 3840;
    int rem = i - seq * 3840;
    int t = rem / 192;
    int k4 = rem - t * 192;
    float4 v = x4[i];
    ushort4 o;
    o.x = f2bf(v.x); o.y = f2bf(v.y); o.z = f2bf(v.z); o.w = f2bf(v.w);
    *reinterpret_cast<ushort4*>(&xb[((size_t)t * 4000 + seq) * 768 + k4 * 4]) = o;
  }
}

// bert-derived: bertW3_bf[b][t][768] = bf16(bert*W3), bertT[b][h][128] = bf16(bert^T)
__global__ __launch_bounds__(256) void prep_bert(const float* __restrict__ bert,
                                                 const float* __restrict__ W3,
                                                 ushort_t* __restrict__ bw3,
                                                 ushort_t* __restrict__ bT) {
  __shared__ ushort_t tl[64 * 130];
  int ht = blockIdx.x, b = blockIdx.y;
  int h0 = ht * 64, tid = threadIdx.x;
  for (int e = tid; e < 8192; e += 256) {
    int t = e >> 6, hh = e & 63;
    float v = bert[((size_t)b * 128 + t) * 768 + h0 + hh];
    bw3[((size_t)b * 128 + t) * 768 + h0 + hh] = f2bf(v * W3[h0 + hh]);
    tl[hh * 130 + t] = f2bf(v);
  }
  __syncthreads();
  for (int e = tid; e < 8192; e += 256) {
    int hh = e >> 7, t = e & 127;
    bT[((size_t)b * 768 + h0 + hh) * 128 + t] = tl[hh * 130 + t];
  }
}

// csT[b][h][128] = bf16(cs[b][p][h])^T, zero-padded p>=100
__global__ __launch_bounds__(256) void csT_k(const ushort_t* __restrict__ csb,
                                             ushort_t* __restrict__ csT) {
  __shared__ ushort_t tl[64 * 130];
  int ht = blockIdx.x, b = blockIdx.y;
  int h0 = ht * 64, tid = threadIdx.x;
  for (int e = tid; e < 6400; e += 256) {
    int p = e >> 6, hh = e & 63;
    tl[hh * 130 + p] = csb[((size_t)b * 100 + p) * 768 + h0 + hh];
  }
  __syncthreads();
  for (int e = tid; e < 8192; e += 256) {
    int hh = e >> 7, p = e & 127;
    csT[((size_t)b * 768 + h0 + hh) * 128 + p] = (p < 100) ? tl[hh * 130 + p] : (ushort_t)0;
  }
}

// ---------------- 128x128 MFMA GEMM (global_load_lds) ----------------
// EPI 0: pre-layout store P[t][seqchunk][nq][off] bf16 (+bias), off=s*16+lk*4+r
// EPI 1: relu(v+bias) f32 (+ optional bf16 copy via C2); EPI 2: relu(v+bias)+resid.
// nbn>0: linear grid + bijective XCD-chunk swizzle (bn fastest within bm).

template <int EPI>
__global__ __launch_bounds__(256) void gemm128(
    const ushort_t* __restrict__ A, int lda,
    const ushort_t* __restrict__ B, int ldb,
    int M, int N, int KT,
    const float* __restrict__ bias,
    const float* __restrict__ resid,
    float* __restrict__ C, int ldc,
    ushort_t* __restrict__ C2,
    int nbn, int swq, int swr)
{
  __shared__ __align__(16) ushort_t lsA[128 * 64];
  __shared__ __align__(16) ushort_t lsB[128 * 64];
  int bm, bn;
  if (nbn > 0) {
    int bid = blockIdx.x, xcd = bid & 7, slot = bid >> 3;
    int L = (xcd < swr) ? xcd * (swq + 1) + slot
                        : swr * (swq + 1) + (xcd - swr) * swq + slot;
    bm = L / nbn; bn = L - bm * nbn;
  } else {
    bm = blockIdx.x; bn = blockIdx.y;
  }
  int m0 = bm * 128, n0 = bn * 128;
  int tid = threadIdx.x, lane = tid & 63, w = tid >> 6;
  int wr = w >> 1, wc = w & 1;
  int l15 = lane & 15, lk = lane >> 4;
  f32x4 acc[4][4];
  #pragma unroll
  for (int i = 0; i < 4; ++i)
    #pragma unroll
    for (int j = 0; j < 4; ++j)
      #pragma unroll
      for (int r = 0; r < 4; ++r) acc[i][j][r] = 0.f;

  int r_in = lane >> 3, p = lane & 7;
  for (int kt = 0; kt < KT; ++kt) {
    __syncthreads();
    #pragma unroll
    for (int i = 0; i < 4; ++i) {
      int seg = w * 4 + i;
      int row = seg * 8 + r_in;
      int sl = p ^ (row & 7);
      int m = m0 + row;
      if (m < M)
        __builtin_amdgcn_global_load_lds(
            (gu32*)(A + (size_t)m * lda + kt * 64 + sl * 8),
            (lu32*)(lsA + seg * 512), 16, 0, 0);
      int n = n0 + row;
      if (n < N)
        __builtin_amdgcn_global_load_lds(
            (gu32*)(B + (size_t)n * ldb + kt * 64 + sl * 8),
            (lu32*)(lsB + seg * 512), 16, 0, 0);
    }
    __syncthreads();
    #pragma unroll
    for (int ks = 0; ks < 2; ++ks) {
      short8 af[4], bfv[4];
      #pragma unroll
      for (int f = 0; f < 4; ++f) {
        int row = wr * 64 + f * 16 + l15;
        af[f] = *reinterpret_cast<const short8*>(
            &lsA[row * 64 + (((ks * 4 + lk) ^ (row & 7)) << 3)]);
        int rowb = wc * 64 + f * 16 + l15;
        bfv[f] = *reinterpret_cast<const short8*>(
            &lsB[rowb * 64 + (((ks * 4 + lk) ^ (rowb & 7)) << 3)]);
      }
      #pragma unroll
      for (int fm = 0; fm < 4; ++fm)
        #pragma unroll
        for (int fn = 0; fn < 4; ++fn)
          acc[fm][fn] = __builtin_amdgcn_mfma_f32_16x16x32_bf16(af[fm], bfv[fn], acc[fm][fn], 0, 0, 0);
    }
  }
  if (EPI == 0) {
    ushort_t* P = (ushort_t*)C;
    #pragma unroll
    for (int fm = 0; fm < 4; ++fm) {
      int mb = m0 + wr * 64 + fm * 16;
      int t = mb / 4000;
      int sq = mb - t * 4000;
      int cch = sq >> 4;
      #pragma unroll
      for (int fn = 0; fn < 4; ++fn) {
        int nb = n0 + wc * 64 + fn * 16;
        if (nb < N) {
          int nl = nb < 400 ? nb : nb - 400;
          int nq = (nb < 400 ? 0 : 25) + (nl >> 4);
          float bsv = bias[nb + l15];
          uint2 pk;
          pk.x = cvtpk(acc[fm][fn][0] + bsv, acc[fm][fn][1] + bsv);
          pk.y = cvtpk(acc[fm][fn][2] + bsv, acc[fm][fn][3] + bsv);
          *reinterpret_cast<uint2*>(
              &P[((((size_t)t * 250 + cch) * 50 + nq) << 8) + l15 * 16 + lk * 4]) = pk;
        }
      }
    }
  } else {
    #pragma unroll
    for (int fm = 0; fm < 4; ++fm)
      #pragma unroll
      for (int fn = 0; fn < 4; ++fn)
        #pragma unroll
        for (int r = 0; r < 4; ++r) {
          int m = m0 + wr * 64 + fm * 16 + lk * 4 + r;
          int n = n0 + wc * 64 + fn * 16 + l15;
          if (m < M && n < N) {
            float v = acc[fm][fn][r] + bias[n];
            v = fmaxf(v, 0.f);
            if (EPI == 2) v += resid[(size_t)m * ldc + n];
            C[(size_t)m * ldc + n] = v;
            if (EPI == 1 && C2) C2[(size_t)m * ldc + n] = f2bf(v);
          }
        }
  }
}

// ---------------- batched 128-tile MFMA GEMM: C[b] = A[b] * B[b]^T ----------------
// M=128 (one m-tile). EPI 10: trilinear total (f32 out, +p1+p2+masks).
// EPI 11: plain bf16 out.

template <int EPI>
__global__ __launch_bounds__(256) void gemm128b(
    const ushort_t* __restrict__ A, long long sA, int lda,
    const ushort_t* __restrict__ Bm, long long sB, int ldb,
    int M, int N, int KT,
    float* __restrict__ Cf, ushort_t* __restrict__ Cb, long long sC, int ldc,
    const float* __restrict__ p1, const float* __restrict__ p2,
    const int* __restrict__ am, const int* __restrict__ cm)
{
  __shared__ __align__(16) ushort_t lsA[128 * 64];
  __shared__ __align__(16) ushort_t lsB[128 * 64];
  int b = blockIdx.z;
  const ushort_t* Ab = A + (size_t)b * sA;
  const ushort_t* Bb = Bm + (size_t)b * sB;
  int n0 = blockIdx.x * 128;
  int tid = threadIdx.x, lane = tid & 63, w = tid >> 6;
  int wr = w >> 1, wc = w & 1;
  int l15 = lane & 15, lk = lane >> 4;
  f32x4 acc[4][4];
  #pragma unroll
  for (int i = 0; i < 4; ++i)
    #pragma unroll
    for (int j = 0; j < 4; ++j)
      #pragma unroll
      for (int r = 0; r < 4; ++r) acc[i][j][r] = 0.f;

  int r_in = lane >> 3, p = lane & 7;
  for (int kt = 0; kt < KT; ++kt) {
    __syncthreads();
    #pragma unroll
    for (int i = 0; i < 4; ++i) {
      int seg = w * 4 + i;
      int row = seg * 8 + r_in;
      int sl = p ^ (row & 7);
      if (row < M)
        __builtin_amdgcn_global_load_lds(
            (gu32*)(Ab + (size_t)row * lda + kt * 64 + sl * 8),
            (lu32*)(lsA + seg * 512), 16, 0, 0);
      int n = n0 + row;
      if (n < N)
        __builtin_amdgcn_global_load_lds(
            (gu32*)(Bb + (size_t)n * ldb + kt * 64 + sl * 8),
            (lu32*)(lsB + seg * 512), 16, 0, 0);
    }
    __syncthreads();
    #pragma unroll
    for (int ks = 0; ks < 2; ++ks) {
      short8 af[4], bfv[4];
      #pragma unroll
      for (int f = 0; f < 4; ++f) {
        int row = wr * 64 + f * 16 + l15;
        af[f] = *reinterpret_cast<const short8*>(
            &lsA[row * 64 + (((ks * 4 + lk) ^ (row & 7)) << 3)]);
        int rowb = wc * 64 + f * 16 + l15;
        bfv[f] = *reinterpret_cast<const short8*>(
            &lsB[rowb * 64 + (((ks * 4 + lk) ^ (rowb & 7)) << 3)]);
      }
      #pragma unroll
      for (int fm = 0; fm < 4; ++fm)
        #pragma unroll
        for (int fn = 0; fn < 4; ++fn)
          acc[fm][fn] = __builtin_amdgcn_mfma_f32_16x16x32_bf16(af[fm], bfv[fn], acc[fm][fn], 0, 0, 0);
    }
  }
  #pragma unroll
  for (int fm = 0; fm < 4; ++fm)
    #pragma unroll
    for (int fn = 0; fn < 4; ++fn)
      #pragma unroll
      for (int r = 0; r < 4; ++r) {
        int m = wr * 64 + fm * 16 + lk * 4 + r;
        int n = n0 + wc * 64 + fn * 16 + l15;
        if (m < M && n < N) {
          float v = acc[fm][fn][r];
          if (EPI == 10) {
            v += p1[b * M + m] + p2[b * N + n];
            v += (1.f - (float)am[b * M + m]) * -10000.f;
            v += (1.f - (float)cm[b * N + n]) * -10000.f;
            Cf[(size_t)b * sC + (size_t)m * ldc + n] = v;
          } else {
            Cb[(size_t)b * sC + (size_t)m * ldc + n] = f2bf(v);
          }
        }
      }
}

// ---------------- fused biLSTM recurrence ----------------

__global__ __launch_bounds__(256) void lstm_recur(
    const ushort_t* __restrict__ pre,    // [20][250][50][256] bf16
    const ushort_t* __restrict__ whh,    // [2][400][128] bf16 (k-padded)
    ushort_t* __restrict__ hcat)         // [4000][256] bf16
{
  __shared__ __align__(16) ushort_t gx[25 * 256];
  __shared__ __align__(16) ushort_t h_lds[16 * 128];

  int dir = blockIdx.y;
  int c = blockIdx.x;
  int tid = threadIdx.x, lane = tid & 63, w = tid >> 6;
  int s = lane & 15, lk = lane >> 4;

  short8 wf[7][4];
  #pragma unroll
  for (int qi = 0; qi < 7; ++qi) {
    int q = w + qi * 4;
    if (q < 25) {
      const ushort_t* wp = whh + ((size_t)dir * 400 + q * 16 + s) * 128;
      #pragma unroll
      for (int ks = 0; ks < 4; ++ks)
        wf[qi][ks] = *reinterpret_cast<const short8*>(wp + ks * 32 + lk * 8);
    }
  }
  for (int e = tid; e < 1024; e += 256)
    *reinterpret_cast<u32*>(&h_lds[e * 2]) = 0u;

  float cst[2][4];
  #pragma unroll
  for (int g = 0; g < 2; ++g)
    #pragma unroll
    for (int r = 0; r < 4; ++r) cst[g][r] = 0.f;

  uint2 pvA[7], pvB[7];
  {
    int tt0 = dir ? 19 : 0;
    const ushort_t* pb = pre + ((((size_t)tt0 * 250 + c) * 50 + dir * 25) << 8);
    #pragma unroll
    for (int qi = 0; qi < 7; ++qi) {
      int q = w + qi * 4;
      if (q < 25) pvA[qi] = *reinterpret_cast<const uint2*>(pb + (q << 8) + s * 16 + lk * 4);
    }
  }
  __syncthreads();

  auto step = [&](uint2 (&pvc)[7], uint2 (&pvn)[7], int t) {
    f32x4 acc[7];
    #pragma unroll
    for (int qi = 0; qi < 7; ++qi)
      #pragma unroll
      for (int r = 0; r < 4; ++r) acc[qi][r] = 0.f;
    #pragma unroll
    for (int ks = 0; ks < 4; ++ks) {
      short8 af = *reinterpret_cast<const short8*>(
          &h_lds[s * 128 + (((ks * 4 + lk) ^ s) << 3)]);
      #pragma unroll
      for (int qi = 0; qi < 7; ++qi)
        if (w + qi * 4 < 25)
          acc[qi] = __builtin_amdgcn_mfma_f32_16x16x32_bf16(af, wf[qi][ks], acc[qi], 0, 0, 0);
    }
    #pragma unroll
    for (int qi = 0; qi < 7; ++qi)
      if (w + qi * 4 < 25) {
        acc[qi][0] += bflo(pvc[qi].x); acc[qi][1] += bfhi(pvc[qi].x);
        acc[qi][2] += bflo(pvc[qi].y); acc[qi][3] += bfhi(pvc[qi].y);
      }
    if (t + 1 < 20) {
      int tn = dir ? 19 - (t + 1) : (t + 1);
      const ushort_t* pb = pre + ((((size_t)tn * 250 + c) * 50 + dir * 25) << 8);
      #pragma unroll
      for (int qi = 0; qi < 7; ++qi) {
        int q = w + qi * 4;
        if (q < 25) pvn[qi] = *reinterpret_cast<const uint2*>(pb + (q << 8) + s * 16 + lk * 4);
      }
    }
    #pragma unroll
    for (int qi = 0; qi < 7; ++qi) {
      int q = w + qi * 4;
      if (q < 25) {
        ushort4 pk;
        pk.x = f2bf(acc[qi][0]); pk.y = f2bf(acc[qi][1]);
        pk.z = f2bf(acc[qi][2]); pk.w = f2bf(acc[qi][3]);
        *reinterpret_cast<ushort4*>(&gx[(q << 8) + s * 16 + lk * 4]) = pk;
      }
    }
    __syncthreads();
    #pragma unroll
    for (int gd = 0; gd < 2; ++gd) {
      int gi = w + gd * 4;
      if (gi < 7) {
        int j = gi * 16 + s;
        if (j < 100) {
          auto ld2 = [&](int q, int sp) {
            return *reinterpret_cast<const uint2*>(&gx[(q << 8) + sp * 16 + lk * 4]);
          };
          uint2 iv = ld2(gi, s);
          uint2 fv = (s < 12) ? ld2(6 + gi, s + 4) : ld2(7 + gi, s - 12);
          uint2 gv = (s < 8) ? ld2(12 + gi, s + 8) : ld2(13 + gi, s - 8);
          uint2 ov = (s < 4) ? ld2(18 + gi, s + 12) : ld2(19 + gi, s - 4);
          float ia[4] = {bflo(iv.x), bfhi(iv.x), bflo(iv.y), bfhi(iv.y)};
          float fa[4] = {bflo(fv.x), bfhi(fv.x), bflo(fv.y), bfhi(fv.y)};
          float ga[4] = {bflo(gv.x), bfhi(gv.x), bflo(gv.y), bfhi(gv.y)};
          float oa[4] = {bflo(ov.x), bfhi(ov.x), bflo(ov.y), bfhi(ov.y)};
          #pragma unroll
          for (int r = 0; r < 4; ++r) {
            float cc = sigm(fa[r]) * cst[gd][r] + sigm(ia[r]) * tanh_f(ga[r]);
            cst[gd][r] = cc;
            int row = lk * 4 + r;
            h_lds[row * 128 + (((j >> 3) ^ row) << 3) + (j & 7)] =
                f2bf(sigm(oa[r]) * tanh_f(cc));
          }
        }
      }
    }
    __syncthreads();
  };

  #pragma unroll 1
  for (int tp = 0; tp < 10; ++tp) {
    step(pvA, pvB, 2 * tp);
    step(pvB, pvA, 2 * tp + 1);
  }

  {
    int row = tid >> 4, sl = tid & 15;
    uint2 v = *reinterpret_cast<const uint2*>(&h_lds[row * 128 + ((sl ^ row) << 3)]);
    *reinterpret_cast<uint2*>(&hcat[(size_t)(c * 16 + row) * 256 + dir * 128 + sl * 8]) = v;
  }
}

// ---------------- small kernels ----------------

__global__ void rowdot(const float* __restrict__ X, int ld, const float* __restrict__ w,
                       const float* __restrict__ b0, float* __restrict__ out, int nrows) {
  int row = blockIdx.x;
  if (row >= nrows) return;
  int lane = threadIdx.x;
  const float* x = X + (size_t)row * ld;
  float s = 0.f;
  for (int k = lane; k < 768; k += 64) s += x[k] * w[k];
  for (int off = 32; off; off >>= 1) s += __shfl_down(s, off);
  if (lane == 0) out[row] = s + b0[0];
}

// merged softmaxes: blocks [0,5120) = over-paths (writes cs_att_bf, padded to 128);
// blocks [5120,9120) = over-tokens (writes ctx_att_bf column p)
__global__ void softmax_both(const float* __restrict__ total,
                             ushort_t* __restrict__ csatt,
                             ushort_t* __restrict__ ctxatt) {
  int bid = blockIdx.x;
  int lane = threadIdx.x;   // 64
  if (bid < 5120) {
    const float* x = total + (size_t)bid * 100;
    float e0 = x[lane];
    bool has1 = (lane + 64) < 100;
    float e1 = has1 ? x[lane + 64] : -3.4e38f;
    float m = fmaxf(e0, e1);
    for (int off = 32; off; off >>= 1) m = fmaxf(m, __shfl_xor(m, off));
    float s0 = expf(e0 - m), s1 = has1 ? expf(e1 - m) : 0.f;
    float s = s0 + s1;
    for (int off = 32; off; off >>= 1) s += __shfl_xor(s, off);
    float inv = 1.f / s;
    csatt[(size_t)bid * 128 + lane] = f2bf(s0 * inv);
    csatt[(size_t)bid * 128 + lane + 64] = has1 ? f2bf(s1 * inv) : (ushort_t)0;
  } else {
    int idx = bid - 5120;
    int b = idx / 100, p = idx - b * 100;
    const float* base = total + (size_t)b * 12800 + p;
    float e0 = base[lane * 100], e1 = base[(lane + 64) * 100];
    float m = fmaxf(e0, e1);
    for (int off = 32; off; off >>= 1) m = fmaxf(m, __shfl_xor(m, off));
    float s0 = expf(e0 - m), s1 = expf(e1 - m);
    float s = s0 + s1;
    for (int off = 32; off; off >>= 1) s += __shfl_xor(s, off);
    float inv = 1.f / s;
    ctxatt[((size_t)b * 128 + lane) * 128 + p] = f2bf(s0 * inv);
    ctxatt[((size_t)b * 128 + lane + 64) * 128 + p] = f2bf(s1 * inv);
  }
}

__global__ void catk(const float* __restrict__ bert, const ushort_t* __restrict__ wcs,
                     const ushort_t* __restrict__ wctx, ushort_t* __restrict__ cat) {
  const int TOT = 5120 * 3072;
  for (int i = blockIdx.x * 256 + threadIdx.x; i < TOT; i += gridDim.x * 256) {
    int row = i / 3072, col = i - row * 3072;
    int seg = col / 768;
    int h = col - seg * 768;
    size_t e = (size_t)row * 768 + h;
    ushort_t o;
    if (seg == 0) o = f2bf(bert[e]);
    else if (seg == 1) o = wcs[e];
    else if (seg == 2) o = f2bf(bert[e] * bflo((u32)wcs[e]));
    else o = f2bf(bert[e] * bflo((u32)wctx[e]));
    cat[i] = o;
  }
}

__global__ __launch_bounds__(256) void layernorm(float* __restrict__ X,
                                                 const float* __restrict__ w,
                                                 const float* __restrict__ bta) {
  int row = blockIdx.x;
  float* x = X + (size_t)row * 768;
  int t = threadIdx.x;
  float v[3];
  float s = 0.f;
  #pragma unroll
  for (int i = 0; i < 3; ++i) { v[i] = x[t + 256 * i]; s += v[i]; }
  __shared__ float red[256];
  red[t] = s; __syncthreads();
  for (int off = 128; off; off >>= 1) { if (t < off) red[t] += red[t + off]; __syncthreads(); }
  float mean = red[0] * (1.f / 768.f);
  __syncthreads();
  float q = 0.f;
  #pragma unroll
  for (int i = 0; i < 3; ++i) { float d = v[i] - mean; q += d * d; }
  red[t] = q; __syncthreads();
  for (int off = 128; off; off >>= 1) { if (t < off) red[t] += red[t + off]; __syncthreads(); }
  float inv = rsqrtf(red[0] * (1.f / 768.f) + 1e-12f);
  #pragma unroll
  for (int i = 0; i < 3; ++i) {
    int k = t + 256 * i;
    x[k] = w[k] * ((v[i] - mean) * inv) + bta[k];
  }
}

// ---------------- host orchestration ----------------

extern "C" void kernel_launch(void* const* d_in, const int* in_sizes, int n_in,
                              void* d_out, int out_size, void* d_ws, size_t ws_size,
                              hipStream_t stream) {
  (void)in_sizes; (void)n_in; (void)out_size; (void)ws_size;
  const float* bert  = (const float*)d_in[0];
  const float* cmn   = (const float*)d_in[1];
  const int*   amask = (const int*)d_in[2];
  const int*   cmask = (const int*)d_in[3];
  const float* Wih_f = (const float*)d_in[8];
  const float* Whh_f = (const float*)d_in[9];
  const float* bih_f = (const float*)d_in[10];
  const float* bhh_f = (const float*)d_in[11];
  const float* Wih_b = (const float*)d_in[12];
  const float* Whh_b = (const float*)d_in[13];
  const float* bih_b = (const float*)d_in[14];
  const float* bhh_b = (const float*)d_in[15];
  const float* projW = (const float*)d_in[16];
  const float* projb = (const float*)d_in[17];
  const float* W1w   = (const float*)d_in[18];
  const float* W1b   = (const float*)d_in[19];
  const float* W2w   = (const float*)d_in[20];
  const float* W2b   = (const float*)d_in[21];
  const float* W3    = (const float*)d_in[22];
  const float* attpW = (const float*)d_in[23];
  const float* attpb = (const float*)d_in[24];
  const float* lnw   = (const float*)d_in[25];
  const float* lnb   = (const float*)d_in[26];

  char* base = (char*)d_ws;
  size_t off = 0;
  auto alloc = [&](size_t bytes) -> char* {
    char* r = base + off;
    off += (bytes + 255) & ~(size_t)255;
    return r;
  };
  ushort_t* wihcat   = (ushort_t*)alloc(800 * 768 * 2);
  ushort_t* whhcat   = (ushort_t*)alloc(800 * 128 * 2);
  float*    biascat  = (float*)alloc(800 * 4);
  ushort_t* projw_bf = (ushort_t*)alloc(768 * 256 * 2);
  ushort_t* attpw_bf = (ushort_t*)alloc(768 * 3072 * 2);
  ushort_t* hcat     = (ushort_t*)alloc(4000 * 256 * 2);
  float*    cs       = (float*)alloc((size_t)4000 * 768 * 4);
  ushort_t* cs_bf    = (ushort_t*)alloc((size_t)4000 * 768 * 2);
  ushort_t* csT      = (ushort_t*)alloc((size_t)40 * 768 * 128 * 2);
  float*    part1    = (float*)alloc(5120 * 4);
  float*    part2    = (float*)alloc(4000 * 4);
  float*    total_s  = (float*)alloc((size_t)40 * 128 * 100 * 4);
  ushort_t* csatt_bf = (ushort_t*)alloc((size_t)40 * 128 * 128 * 2);
  ushort_t* ctxatt_bf= (ushort_t*)alloc((size_t)40 * 128 * 128 * 2);
  ushort_t* probs_bf = (ushort_t*)alloc((size_t)40 * 128 * 128 * 2);
  ushort_t* wcs_bf   = (ushort_t*)alloc((size_t)40 * 128 * 768 * 2);
  ushort_t* wctx_bf  = (ushort_t*)alloc((size_t)40 * 128 * 768 * 2);
  ushort_t* bw3_bf   = (ushort_t*)alloc((size_t)40 * 128 * 768 * 2);
  ushort_t* bertT    = (ushort_t*)alloc((size_t)40 * 768 * 128 * 2);
  ushort_t* cat      = (ushort_t*)alloc((size_t)5120 * 3072 * 2);
  ushort_t* x_bf     = (ushort_t*)alloc((size_t)20 * 4000 * 768 * 2);
  ushort_t* pre      = (ushort_t*)alloc((size_t)20 * 250 * 50 * 256 * 2);

  prep_weights<<<512, 256, 0, stream>>>(Wih_f, Wih_b, Whh_f, Whh_b, bih_f, bhh_f, bih_b, bhh_b,
                                        projW, attpW, wihcat, whhcat, biascat, projw_bf, attpw_bf);
  prep_bert<<<dim3(12, 40), 256, 0, stream>>>(bert, W3, bw3_bf, bertT);
  convert_x_t<<<2048, 256, 0, stream>>>((const float4*)cmn, x_bf);

  // pre = x @ Wih^T + (bih+bhh); XCD-chunked grid (nwg=4375, q=546, r=7)
  gemm128<0><<<4375, 256, 0, stream>>>(x_bf, 768, wihcat, 768, 80000, 800, 12,
                                       biascat, nullptr, (float*)pre, 0, nullptr, 7, 546, 7);
  lstm_recur<<<dim3(250, 2), 256, 0, stream>>>(pre, whhcat, hcat);

  // cs = relu(hcat @ projW^T + projb): f32 + bf16 copies
  gemm128<1><<<dim3(32, 6), 256, 0, stream>>>(hcat, 256, projw_bf, 256, 4000, 768, 4,
                                              projb, nullptr, cs, 768, cs_bf, 0, 0, 0);
  csT_k<<<dim3(12, 40), 256, 0, stream>>>(cs_bf, csT);
  rowdot<<<5120, 64, 0, stream>>>(bert, 768, W1w, W1b, part1, 5120);
  rowdot<<<4000, 64, 0, stream>>>(cs, 768, W2w, W2b, part2, 4000);

  // total[b,s,p] = (W3*bert) @ cs^T + part1 + part2 + masks   (MFMA, K=768)
  gemm128b<10><<<dim3(1, 1, 40), 256, 0, stream>>>(
      bw3_bf, 98304LL, 768, cs_bf, 76800LL, 768, 128, 100, 12,
      total_s, nullptr, 12800LL, 100, part1, part2, amask, cmask);
  softmax_both<<<9120, 64, 0, stream>>>(total_s, csatt_bf, ctxatt_bf);
  // weight_cs[b,s,h] = cs_att @ cs   (A=cs_att[128][128pad], B=csT[768][128])
  gemm128b<11><<<dim3(6, 1, 40), 256, 0, stream>>>(
      csatt_bf, 16384LL, 128, csT, 98304LL, 128, 128, 768, 2,
      nullptr, wcs_bf, 98304LL, 768, nullptr, nullptr, nullptr, nullptr);
  // probs[b,s,t] = cs_att @ ctx_att^T   (B=ctx_att[t][p] natural)
  gemm128b<11><<<dim3(1, 1, 40), 256, 0, stream>>>(
      csatt_bf, 16384LL, 128, ctxatt_bf, 16384LL, 128, 128, 128, 2,
      nullptr, probs_bf, 16384LL, 128, nullptr, nullptr, nullptr, nullptr);
  // weighted_context[b,s,h] = probs @ bert   (B=bertT[h][t])
  gemm128b<11><<<dim3(6, 1, 40), 256, 0, stream>>>(
      probs_bf, 16384LL, 128, bertT, 98304LL, 128, 128, 768, 2,
      nullptr, wctx_bf, 98304LL, 768, nullptr, nullptr, nullptr, nullptr);

  catk<<<2048, 256, 0, stream>>>(bert, wcs_bf, wctx_bf, cat);
  gemm128<2><<<240, 256, 0, stream>>>(cat, 3072, attpw_bf, 3072, 5120, 768, 48,
                                      attpb, bert, (float*)d_out, 768, nullptr, 6, 30, 0);
  layernorm<<<5120, 256, 0, stream>>>((float*)d_out, lnw, lnb);
}